// Round 5
// baseline (332.892 us; speedup 1.0000x reference)
//
#include <hip/hip_runtime.h>
#include <hip/hip_bf16.h>

// SignAttention on MI355X, round 5.
// Change vs r4: attn_fused decomposed into qk_soft (GEMM + in-register
// chunk-softmax epilogue + LDS-bounce transposed attnT write) and pv
// (plain NT GEMM O^T = attnT @ V^T), batched over b to bound the attnT
// scratch. Every kernel is a short 2-barrier m97-style GEMM with small LDS
// and high occupancy. Other kernels identical to the passing r3/r4 set.

using bf16x8 = __attribute__((ext_vector_type(8))) __bf16;
using f32x4  = __attribute__((ext_vector_type(4))) float;
using s16x4  = __attribute__((ext_vector_type(4))) short;

static __device__ __forceinline__ short f2b(float f) {  // fp32 -> bf16, RNE
  union { float f; unsigned u; } v; v.f = f;
  unsigned r = v.u + 0x7fffu + ((v.u >> 16) & 1u);
  return (short)(r >> 16);
}

static __device__ __forceinline__ void gll16(const void* g, void* l) {
  __builtin_amdgcn_global_load_lds(
      (const __attribute__((address_space(1))) void*)g,
      (__attribute__((address_space(3))) void*)l, 16, 0, 0);
}

#define MFMA16(a, b, c) __builtin_amdgcn_mfma_f32_16x16x32_bf16((a), (b), (c), 0, 0, 0)

// ---------------- elementwise fp32 -> bf16 ----------------
__global__ __launch_bounds__(256) void cvt_bf16(const float* __restrict__ in,
                                                short* __restrict__ out, int n) {
  int i = (blockIdx.x * 256 + threadIdx.x) * 4;
  if (i >= n) return;
  float4 v = *(const float4*)(in + i);
  s16x4 s = { f2b(v.x), f2b(v.y), f2b(v.z), f2b(v.w) };
  *(s16x4*)(out + i) = s;
}

// ------- 64x64-tile convert (+optional plain bf16 copy) + transpose -------
__global__ __launch_bounds__(256) void tcvt(const float* __restrict__ in,
    short* __restrict__ outP, short* __restrict__ outT,
    int R, int C, long inB, long pB, long tB)
{
  __shared__ short tile[64][68];
  long bz = blockIdx.z;
  const float* src = in + bz * inB;
  int r0 = blockIdx.y * 64, c0 = blockIdx.x * 64;
  int t = threadIdx.x;
  int r = t >> 2, cq = (t & 3) * 16;
  #pragma unroll
  for (int e = 0; e < 16; e += 4) {
    float4 v = *(const float4*)(&src[(long)(r0 + r) * C + (c0 + cq + e)]);
    s16x4 s = { f2b(v.x), f2b(v.y), f2b(v.z), f2b(v.w) };
    *(s16x4*)(&tile[r][cq + e]) = s;
    if (outP) *(s16x4*)(&outP[bz * pB + (long)(r0 + r) * C + (c0 + cq + e)]) = s;
  }
  __syncthreads();
  int tr = t >> 2, re = (t & 3) * 16;
  short tmp[16];
  #pragma unroll
  for (int e = 0; e < 16; ++e) tmp[e] = tile[re + e][tr];
  short* dst = &outT[bz * tB + (long)(c0 + tr) * R + (r0 + re)];
  #pragma unroll
  for (int e = 0; e < 16; e += 4) *(s16x4*)(&dst[e]) = *(const s16x4*)(&tmp[e]);
}

// ---------------- generic batched NT GEMM, m97 structure ----------------
template<bool F32OUT>
__global__ __launch_bounds__(256) void gemm_nt(
    const short* __restrict__ A, const short* __restrict__ B,
    void* __restrict__ C, const float* __restrict__ bias,
    int M, int N, int K, int lda, int ldb, int ldc,
    long aSB, long aSH, long bSB, long bSH, long cSB, long cSH, int nh)
{
  int batch = blockIdx.z;
  int hb = batch % nh, bb = batch / nh;
  const short* Ab = A + bb * aSB + hb * aSH;
  const short* Bb = B + bb * bSB + hb * bSH;
  long cOff = bb * cSB + hb * cSH;
  int m0 = blockIdx.y * 128, n0 = blockIdx.x * 128;
  __shared__ short As[128 * 64];
  __shared__ short Bs[128 * 64];
  int t = threadIdx.x;
  int lane = t & 63, wid = t >> 6;
  int wm = (wid >> 1) * 64, wn = (wid & 1) * 64;
  int rl = lane & 15, q = lane >> 4;
  f32x4 acc[4][4] = {};
  for (int k0 = 0; k0 < K; k0 += 64) {
    __syncthreads();
    #pragma unroll
    for (int j = 0; j < 4; ++j) {
      int g = j * 256 + t;
      int r = g >> 3, cc = g & 7;
      int cs = cc ^ (r & 7);
      gll16(&Ab[(long)(m0 + r) * lda + k0 + cs * 8], (char*)As + (j * 256 + wid * 64) * 16);
      gll16(&Bb[(long)(n0 + r) * ldb + k0 + cs * 8], (char*)Bs + (j * 256 + wid * 64) * 16);
    }
    __syncthreads();
    #pragma unroll
    for (int kt = 0; kt < 2; ++kt) {
      int cq = kt * 4 + q;
      bf16x8 af[4], bfv[4];
      #pragma unroll
      for (int mi = 0; mi < 4; ++mi) {
        int R = wm + 16 * mi + rl;
        af[mi] = *(const bf16x8*)((const char*)As + (R * 8 + (cq ^ (R & 7))) * 16);
      }
      #pragma unroll
      for (int ni = 0; ni < 4; ++ni) {
        int RN = wn + 16 * ni + rl;
        bfv[ni] = *(const bf16x8*)((const char*)Bs + (RN * 8 + (cq ^ (RN & 7))) * 16);
      }
      #pragma unroll
      for (int mi = 0; mi < 4; ++mi)
        #pragma unroll
        for (int ni = 0; ni < 4; ++ni)
          acc[mi][ni] = MFMA16(af[mi], bfv[ni], acc[mi][ni]);
    }
  }
  #pragma unroll
  for (int mi = 0; mi < 4; ++mi)
    #pragma unroll
    for (int ni = 0; ni < 4; ++ni)
      #pragma unroll
      for (int r = 0; r < 4; ++r) {
        int row = m0 + wm + 16 * mi + 4 * q + r;
        int col = n0 + wn + 16 * ni + rl;
        float val = acc[mi][ni][r];
        if (F32OUT) {
          ((float*)C)[cOff + (long)row * ldc + col] = val + (bias ? bias[row] : 0.f);
        } else {
          ((short*)C)[cOff + (long)row * ldc + col] = f2b(val);
        }
      }
}

// ---- qk_soft: S-tile = Wk[i-tile] @ G[c-chunk], chunk-softmax, attnT out ----
// grid (c=8, it=8, z=NZ bh). 4 waves; wave = 32 i x 128 j (full chunk width,
// softmax entirely within wave). LDS 32KB: As/Bs [128][64] -> aT [128][128].
__global__ __launch_bounds__(256) void qk_soft(
    const short* __restrict__ Wk, const short* __restrict__ GT,
    short* __restrict__ attnT)
{
  __shared__ short smem[16384];  // As | Bs, reused as aT [128 j][128 i]
  short* As = smem;
  short* Bs = smem + 8192;
  int c = blockIdx.x, it = blockIdx.y, z = blockIdx.z;
  int h = z & 7;
  int t = threadIdx.x, lane = t & 63, w = t >> 6;
  int rl = lane & 15, q = lane >> 4;
  const short* Ab = Wk + (long)(h * 1024 + it * 128) * 256;
  const short* Bb = GT + ((long)z * 1024 + c * 128) * 256;
  const float SC = 1.4426950408889634f / 32.0f;  // log2(e)/sqrt(dk)
  f32x4 s[2][8] = {};
  for (int k0 = 0; k0 < 256; k0 += 64) {
    __syncthreads();
    #pragma unroll
    for (int j = 0; j < 4; ++j) {
      int g = j * 256 + t;
      int r = g >> 3, cc = g & 7, cs = cc ^ (r & 7);
      gll16(&Ab[(long)r * 256 + k0 + cs * 8], (char*)As + (j * 256 + w * 64) * 16);
      gll16(&Bb[(long)r * 256 + k0 + cs * 8], (char*)Bs + (j * 256 + w * 64) * 16);
    }
    __syncthreads();
    #pragma unroll
    for (int kt = 0; kt < 2; ++kt) {
      int cq = kt * 4 + q;
      bf16x8 af[2];
      #pragma unroll
      for (int mi = 0; mi < 2; ++mi) {
        int R = 32 * w + 16 * mi + rl;
        af[mi] = *(const bf16x8*)((const char*)As + (R * 8 + (cq ^ (R & 7))) * 16);
      }
      #pragma unroll
      for (int ni = 0; ni < 8; ++ni) {
        int RN = 16 * ni + rl;
        bf16x8 bv = *(const bf16x8*)((const char*)Bs + (RN * 8 + (cq ^ (RN & 7))) * 16);
        #pragma unroll
        for (int mi = 0; mi < 2; ++mi)
          s[mi][ni] = MFMA16(af[mi], bv, s[mi][ni]);
      }
    }
  }
  __syncthreads();  // all LDS reads done before aT alias reuse
  // ---- softmax over 128 j per row (row = 32w+16mi+4q+r) ----
  float mx[2][4], sm[2][4], rc[2][4];
  #pragma unroll
  for (int mi = 0; mi < 2; ++mi)
    #pragma unroll
    for (int r = 0; r < 4; ++r) {
      float m = s[mi][0][r];
      #pragma unroll
      for (int ni = 1; ni < 8; ++ni) m = fmaxf(m, s[mi][ni][r]);
      mx[mi][r] = m;
    }
  #pragma unroll
  for (int msk = 1; msk < 16; msk <<= 1)
    #pragma unroll
    for (int mi = 0; mi < 2; ++mi)
      #pragma unroll
      for (int r = 0; r < 4; ++r)
        mx[mi][r] = fmaxf(mx[mi][r], __shfl_xor(mx[mi][r], msk, 64));
  #pragma unroll
  for (int mi = 0; mi < 2; ++mi)
    #pragma unroll
    for (int r = 0; r < 4; ++r) sm[mi][r] = 0.f;
  #pragma unroll
  for (int mi = 0; mi < 2; ++mi)
    #pragma unroll
    for (int ni = 0; ni < 8; ++ni)
      #pragma unroll
      for (int r = 0; r < 4; ++r) {
        float p = exp2f((s[mi][ni][r] - mx[mi][r]) * SC);
        s[mi][ni][r] = p;
        sm[mi][r] += p;
      }
  #pragma unroll
  for (int msk = 1; msk < 16; msk <<= 1)
    #pragma unroll
    for (int mi = 0; mi < 2; ++mi)
      #pragma unroll
      for (int r = 0; r < 4; ++r)
        sm[mi][r] += __shfl_xor(sm[mi][r], msk, 64);
  #pragma unroll
  for (int mi = 0; mi < 2; ++mi)
    #pragma unroll
    for (int r = 0; r < 4; ++r) rc[mi][r] = __builtin_amdgcn_rcpf(sm[mi][r]);
  // ---- write attn^T into aT (swizzled): aT[j][i_loc], i_loc = 32w+16mi+4q+r
  #pragma unroll
  for (int mi = 0; mi < 2; ++mi)
    #pragma unroll
    for (int ni = 0; ni < 8; ++ni) {
      s16x4 pk = { f2b(s[mi][ni][0] * rc[mi][0]), f2b(s[mi][ni][1] * rc[mi][1]),
                   f2b(s[mi][ni][2] * rc[mi][2]), f2b(s[mi][ni][3] * rc[mi][3]) };
      int j  = 16 * ni + rl;
      int ci = 4 * w + 2 * mi + (q >> 1);
      *(s16x4*)((char*)smem + j * 256 + ((ci ^ (j & 7)) * 16) + (q & 1) * 8) = pk;
    }
  __syncthreads();
  // ---- coalesced copy aT -> attnT[z][c*128 + j][it*128 + i] ----
  int j = t >> 1, half = t & 1;
  long base = ((long)z * 1024 + c * 128 + j) * 1024 + it * 128 + half * 64;
  #pragma unroll
  for (int e = 0; e < 8; ++e) {
    int ch = half * 8 + e;
    int4 v = *(const int4*)((const char*)smem + j * 256 + (ch ^ (j & 7)) * 16);
    *(int4*)(&attnT[base + e * 8]) = v;
  }
}

// ---- pv: O^T[j][d] = attnT[j][:] . V[d][:]  (NT GEMM, tile 32j x 64d) ----
// grid (jt=32, 1, z=NZ bh). LDS 12KB: As[32][64], Bs[64][64].
__global__ __launch_bounds__(256) void pv(
    const short* __restrict__ attnT, const short* __restrict__ V,
    short* __restrict__ OT)
{
  __shared__ short smem[6144];
  short* As = smem;            // [32][64]
  short* Bs = smem + 2048;     // [64][64]
  int jt = blockIdx.x, z = blockIdx.z;
  int bl = z >> 3, h = z & 7;
  int t = threadIdx.x, lane = t & 63, w = t >> 6;
  int rl = lane & 15, q = lane >> 4;
  int wj = (w >> 1) * 16, wd = (w & 1) * 32;
  const short* Ab = attnT + ((long)z * 1024 + jt * 32) * 1024;
  const short* Bb = V + (long)(bl * 512 + h * 64) * 1024;
  short* Ob = OT + (long)(bl * 1024 + jt * 32) * 512 + h * 64;
  f32x4 acc[2] = {};
  for (int k0 = 0; k0 < 1024; k0 += 64) {
    __syncthreads();
    {
      int r = t >> 3, cc = t & 7, cs = cc ^ (r & 7);
      gll16(&Ab[(long)r * 1024 + k0 + cs * 8], (char*)As + (w * 64) * 16);
    }
    #pragma unroll
    for (int j = 0; j < 2; ++j) {
      int g = j * 256 + t;
      int r = g >> 3, cc = g & 7, cs = cc ^ (r & 7);
      gll16(&Bb[(long)r * 1024 + k0 + cs * 8], (char*)Bs + (j * 256 + w * 64) * 16);
    }
    __syncthreads();
    #pragma unroll
    for (int kt = 0; kt < 2; ++kt) {
      int cq = kt * 4 + q;
      int R = wj + rl;
      bf16x8 af = *(const bf16x8*)((const char*)As + (R * 8 + (cq ^ (R & 7))) * 16);
      #pragma unroll
      for (int nd = 0; nd < 2; ++nd) {
        int RN = wd + 16 * nd + rl;
        bf16x8 bv = *(const bf16x8*)((const char*)Bs + (RN * 8 + (cq ^ (RN & 7))) * 16);
        acc[nd] = MFMA16(af, bv, acc[nd]);
      }
    }
  }
  #pragma unroll
  for (int nd = 0; nd < 2; ++nd)
    #pragma unroll
    for (int r = 0; r < 4; ++r) {
      int jl = wj + 4 * q + r;
      int d  = wd + 16 * nd + rl;
      Ob[(long)jl * 512 + d] = f2b(acc[nd][r]);
    }
}

extern "C" void kernel_launch(void* const* d_in, const int* in_sizes, int n_in,
                              void* d_out, int out_size, void* d_ws, size_t ws_size,
                              hipStream_t stream)
{
  const float* x  = (const float*)d_in[0];
  const float* Wk = (const float*)d_in[1];
  const float* Wq = (const float*)d_in[2];
  const float* Wv = (const float*)d_in[3];
  const float* Wr = (const float*)d_in[4];
  const float* br = (const float*)d_in[5];
  float* out = (float*)d_out;

  char* ws = (char*)d_ws;
  short* Xbf = (short*)(ws + 0);         // [8][256][1024]   (dead after M-gemm)
  short* XT  = (short*)(ws + 4194304);   // [8][1024][256]   (dead after V-gemm)
  short* WqT = (short*)(ws + 8388608);   // [256][8192]      (dead after M-gemm)
  short* Wkb = (short*)(ws + 12582912);  // [8192][256]
  short* Wvb = (short*)(ws + 16777216);  // [512][256]
  short* Wrb = (short*)(ws + 17039360);  // [256][512]
  short* Mb  = (short*)(ws + 17301504);  // [8][8][256][256]
  short* GTb = (short*)(ws + 25690112);  // [8][8][1024][256]
  short* Vbf = (short*)(ws + 59244544);  // [8][512][1024]
  short* OTb = (short*)(ws + 67633152);  // [8][1024][512]

  // attnT scratch: big-ws path uses the tail (4 batches of 16 bh);
  // small-ws path reuses [0, 16MB) (Xbf/XT/WqT, dead by then; 8 batches of 8 bh)
  bool big = ws_size >= (size_t)110000000;
  short* attnT = big ? (short*)(ws + 76021760) : (short*)ws;
  int NB = big ? 4 : 8;
  int NZ = big ? 16 : 8;

  // converts / transposes
  tcvt<<<dim3(16, 4, 8), 256, 0, stream>>>(x, Xbf, XT, 256, 1024, 262144L, 262144L, 262144L);
  tcvt<<<dim3(4, 128, 1), 256, 0, stream>>>(Wq, nullptr, WqT, 8192, 256, 0L, 0L, 0L);
  cvt_bf16<<<2048, 256, 0, stream>>>(Wk, Wkb, 2097152);
  cvt_bf16<<<128, 256, 0, stream>>>(Wv, Wvb, 131072);
  cvt_bf16<<<128, 256, 0, stream>>>(Wr, Wrb, 131072);

  // M[b,h] = X_b @ Wq_h            (256x256, K=1024)
  gemm_nt<false><<<dim3(2, 2, 64), 256, 0, stream>>>(Xbf, WqT, Mb, nullptr,
      256, 256, 1024, 1024, 8192, 256,
      262144L, 0L, 0L, 1024L, 524288L, 65536L, 8);
  // G^T[b,h] = X_b^T @ M           (1024x256, K=256)
  gemm_nt<false><<<dim3(2, 8, 64), 256, 0, stream>>>(XT, Mb, GTb, nullptr,
      1024, 256, 256, 256, 256, 256,
      262144L, 0L, 524288L, 65536L, 2097152L, 262144L, 8);
  // V[b] = Wv @ X_b                (512x1024, K=256)
  gemm_nt<false><<<dim3(8, 4, 8), 256, 0, stream>>>(Wvb, XT, Vbf, nullptr,
      512, 1024, 256, 256, 256, 1024,
      0L, 0L, 262144L, 0L, 524288L, 0L, 1);

  // batched qk_soft + pv (attnT reused per batch; stream order serializes)
  for (int bb = 0; bb < NB; ++bb) {
    qk_soft<<<dim3(8, 8, NZ), 256, 0, stream>>>(
        Wkb, GTb + (long)bb * NZ * 262144, attnT);
    pv<<<dim3(32, 1, NZ), 256, 0, stream>>>(
        attnT, Vbf + (long)bb * NZ * 65536, OTb + (long)bb * NZ * 65536);
  }

  // Y[b] = Wr @ O_b + br           (256x1024, K=512) -> d_out fp32
  gemm_nt<true><<<dim3(8, 2, 8), 256, 0, stream>>>(Wrb, OTb, out, br,
      256, 1024, 512, 512, 512, 1024,
      0L, 0L, 524288L, 0L, 262144L, 0L, 1);
}

// Round 7
// 314.091 us; speedup vs baseline: 1.0599x; 1.0599x over previous
//
#include <hip/hip_runtime.h>
#include <hip/hip_bf16.h>

// SignAttention on MI355X, round 7 (= round-6 kernel + cvt_o grid fix;
// r6 never ran: GPU acquisition timeout).
// vs r5: qk_soft+pv batch loop replaced by ONE qk_pv launch (2048 blocks,
// split-K over i, fp32 atomicAdd into O32 laid over dead ws regions), no
// attnT round-trip. cvts merged (3->1 launch); M/V/final gemms get BM=64
// tiles (2x grid). 10 launches total.

using bf16x8 = __attribute__((ext_vector_type(8))) __bf16;
using f32x4  = __attribute__((ext_vector_type(4))) float;
using s16x4  = __attribute__((ext_vector_type(4))) short;

static __device__ __forceinline__ short f2b(float f) {  // fp32 -> bf16, RNE
  union { float f; unsigned u; } v; v.f = f;
  unsigned r = v.u + 0x7fffu + ((v.u >> 16) & 1u);
  return (short)(r >> 16);
}

static __device__ __forceinline__ void gll16(const void* g, void* l) {
  __builtin_amdgcn_global_load_lds(
      (const __attribute__((address_space(1))) void*)g,
      (__attribute__((address_space(3))) void*)l, 16, 0, 0);
}

#define MFMA16(a, b, c) __builtin_amdgcn_mfma_f32_16x16x32_bf16((a), (b), (c), 0, 0, 0)

// ---------------- fused fp32->bf16 for Wk|Wv|Wr in one launch ----------------
__global__ __launch_bounds__(256) void cvt3(
    const float* __restrict__ wk, short* __restrict__ wko,
    const float* __restrict__ wv, short* __restrict__ wvo,
    const float* __restrict__ wr, short* __restrict__ wro) {
  int bx = blockIdx.x;
  const float* in; short* out; int base;
  if (bx < 2048)      { in = wk; out = wko; base = bx; }
  else if (bx < 2176) { in = wv; out = wvo; base = bx - 2048; }
  else                { in = wr; out = wro; base = bx - 2176; }
  int i = base * 1024 + threadIdx.x * 4;
  float4 v = *(const float4*)(in + i);
  s16x4 s = { f2b(v.x), f2b(v.y), f2b(v.z), f2b(v.w) };
  *(s16x4*)(out + i) = s;
}

// ------- 64x64-tile convert (+optional plain bf16 copy) + transpose -------
__global__ __launch_bounds__(256) void tcvt(const float* __restrict__ in,
    short* __restrict__ outP, short* __restrict__ outT,
    int R, int C, long inB, long pB, long tB)
{
  __shared__ short tile[64][68];
  long bz = blockIdx.z;
  const float* src = in + bz * inB;
  int r0 = blockIdx.y * 64, c0 = blockIdx.x * 64;
  int t = threadIdx.x;
  int r = t >> 2, cq = (t & 3) * 16;
  #pragma unroll
  for (int e = 0; e < 16; e += 4) {
    float4 v = *(const float4*)(&src[(long)(r0 + r) * C + (c0 + cq + e)]);
    s16x4 s = { f2b(v.x), f2b(v.y), f2b(v.z), f2b(v.w) };
    *(s16x4*)(&tile[r][cq + e]) = s;
    if (outP) *(s16x4*)(&outP[bz * pB + (long)(r0 + r) * C + (c0 + cq + e)]) = s;
  }
  __syncthreads();
  int tr = t >> 2, re = (t & 3) * 16;
  short tmp[16];
  #pragma unroll
  for (int e = 0; e < 16; ++e) tmp[e] = tile[re + e][tr];
  short* dst = &outT[bz * tB + (long)(c0 + tr) * R + (r0 + re)];
  #pragma unroll
  for (int e = 0; e < 16; e += 4) *(s16x4*)(&dst[e]) = *(const s16x4*)(&tmp[e]);
}

// ---------------- generic batched NT GEMM, m97 structure, BM templated ------
template<int BM, bool F32OUT>
__global__ __launch_bounds__(256) void gemm_nt(
    const short* __restrict__ A, const short* __restrict__ B,
    void* __restrict__ C, const float* __restrict__ bias,
    int M, int N, int K, int lda, int ldb, int ldc,
    long aSB, long aSH, long bSB, long bSH, long cSB, long cSH, int nh)
{
  constexpr int MI = BM / 32;       // A fragments per wave
  int batch = blockIdx.z;
  int hb = batch % nh, bb = batch / nh;
  const short* Ab = A + bb * aSB + hb * aSH;
  const short* Bb = B + bb * bSB + hb * bSH;
  long cOff = bb * cSB + hb * cSH;
  int m0 = blockIdx.y * BM, n0 = blockIdx.x * 128;
  __shared__ short As[BM * 64];
  __shared__ short Bs[128 * 64];
  int t = threadIdx.x;
  int lane = t & 63, wid = t >> 6;
  int wm = (wid >> 1) * (BM / 2), wn = (wid & 1) * 64;
  int rl = lane & 15, q = lane >> 4;
  f32x4 acc[MI][4] = {};
  for (int k0 = 0; k0 < K; k0 += 64) {
    __syncthreads();
    #pragma unroll
    for (int j = 0; j < BM / 32; ++j) {
      int g = j * 256 + t;
      int r = g >> 3, cc = g & 7;
      int cs = cc ^ (r & 7);
      gll16(&Ab[(long)(m0 + r) * lda + k0 + cs * 8], (char*)As + (j * 256 + wid * 64) * 16);
    }
    #pragma unroll
    for (int j = 0; j < 4; ++j) {
      int g = j * 256 + t;
      int r = g >> 3, cc = g & 7;
      int cs = cc ^ (r & 7);
      gll16(&Bb[(long)(n0 + r) * ldb + k0 + cs * 8], (char*)Bs + (j * 256 + wid * 64) * 16);
    }
    __syncthreads();
    #pragma unroll
    for (int kt = 0; kt < 2; ++kt) {
      int cq = kt * 4 + q;
      bf16x8 af[MI], bfv[4];
      #pragma unroll
      for (int mi = 0; mi < MI; ++mi) {
        int R = wm + 16 * mi + rl;
        af[mi] = *(const bf16x8*)((const char*)As + (R * 8 + (cq ^ (R & 7))) * 16);
      }
      #pragma unroll
      for (int ni = 0; ni < 4; ++ni) {
        int RN = wn + 16 * ni + rl;
        bfv[ni] = *(const bf16x8*)((const char*)Bs + (RN * 8 + (cq ^ (RN & 7))) * 16);
      }
      #pragma unroll
      for (int mi = 0; mi < MI; ++mi)
        #pragma unroll
        for (int ni = 0; ni < 4; ++ni)
          acc[mi][ni] = MFMA16(af[mi], bfv[ni], acc[mi][ni]);
    }
  }
  #pragma unroll
  for (int mi = 0; mi < MI; ++mi)
    #pragma unroll
    for (int ni = 0; ni < 4; ++ni)
      #pragma unroll
      for (int r = 0; r < 4; ++r) {
        int row = m0 + wm + 16 * mi + 4 * q + r;
        int col = n0 + wn + 16 * ni + rl;
        float val = acc[mi][ni][r];
        if (F32OUT) {
          ((float*)C)[cOff + (long)row * ldc + col] = val + (bias ? bias[row] : 0.f);
        } else {
          ((short*)C)[cOff + (long)row * ldc + col] = f2b(val);
        }
      }
}

// ---------------- zero the fp32 O accumulator (split placement) -------------
__global__ __launch_bounds__(256) void zero_o(float* __restrict__ lo,
                                              float* __restrict__ hi) {
  int z = blockIdx.y;
  float* oz = (z < 48) ? lo + (long)z * 65536 : hi + (long)(z - 48) * 65536;
  int idx = (blockIdx.x * 256 + threadIdx.x) * 4;
  float4 zz = {0.f, 0.f, 0.f, 0.f};
  *(float4*)(oz + idx) = zz;
}

// ---- qk_pv: S = Wk[ih-slab] @ G[c-chunk]; chunk-softmax; PV partial with
// ---- fp32 atomicAdd into O32[z][j][d]. grid 2048 1D (c fastest => XCD=c).
__global__ __launch_bounds__(256) void qk_pv(
    const short* __restrict__ Wk, const short* __restrict__ GT,
    const short* __restrict__ V, float* __restrict__ o32lo,
    float* __restrict__ o32hi)
{
  __shared__ short smem[24576];  // 48 KiB: As [256][64] | Bs [128][64]
  short* As = smem;
  short* Bs = smem + 16384;
  short* aT = smem;              // [128 j][128 i], aliases As after QK
  int wg = blockIdx.x;
  int c = wg & 7, b = (wg >> 3) & 7, ih = (wg >> 6) & 3, h = wg >> 8;
  int z = b * 8 + h;
  int t = threadIdx.x, lane = t & 63, w = t >> 6;
  int rl = lane & 15, q = lane >> 4;
  const short* Ab = Wk + (long)(h * 1024 + ih * 256) * 256;
  const short* Bb = GT + ((long)z * 1024 + c * 128) * 256;
  const short* Vb = V + (long)(b * 512 + h * 64) * 1024;
  float* Oz = (z < 48) ? o32lo + (long)z * 65536 : o32hi + (long)(z - 48) * 65536;
  const float SC = 1.4426950408889634f / 32.0f;  // log2(e)/sqrt(dk)

  f32x4 s[4][8] = {};
  for (int k0 = 0; k0 < 256; k0 += 64) {
    __syncthreads();
    #pragma unroll
    for (int j = 0; j < 8; ++j) {
      int g = j * 256 + t;
      int r = g >> 3, cc = g & 7, cs = cc ^ (r & 7);
      gll16(&Ab[(long)r * 256 + k0 + cs * 8], (char*)As + (j * 256 + w * 64) * 16);
    }
    #pragma unroll
    for (int j = 0; j < 4; ++j) {
      int g = j * 256 + t;
      int r = g >> 3, cc = g & 7, cs = cc ^ (r & 7);
      gll16(&Bb[(long)r * 256 + k0 + cs * 8], (char*)Bs + (j * 256 + w * 64) * 16);
    }
    __syncthreads();
    #pragma unroll
    for (int kt = 0; kt < 2; ++kt) {
      int cq = kt * 4 + q;
      bf16x8 af[4];
      #pragma unroll
      for (int mi = 0; mi < 4; ++mi) {
        int R = w * 64 + 16 * mi + rl;
        af[mi] = *(const bf16x8*)((const char*)As + (R * 8 + (cq ^ (R & 7))) * 16);
      }
      #pragma unroll
      for (int ni = 0; ni < 8; ++ni) {
        int RN = 16 * ni + rl;
        bf16x8 bv = *(const bf16x8*)((const char*)Bs + (RN * 8 + (cq ^ (RN & 7))) * 16);
        #pragma unroll
        for (int mi = 0; mi < 4; ++mi)
          s[mi][ni] = MFMA16(af[mi], bv, s[mi][ni]);
      }
    }
  }
  __syncthreads();  // all QK LDS reads done before aT alias reuse

  // ---- softmax over the 128 cols, per row (row = 64w+16mi+4q+r) ----
  float mx[4][4], sm[4][4], rc[4][4];
  #pragma unroll
  for (int mi = 0; mi < 4; ++mi)
    #pragma unroll
    for (int r = 0; r < 4; ++r) {
      float m = s[mi][0][r];
      #pragma unroll
      for (int ni = 1; ni < 8; ++ni) m = fmaxf(m, s[mi][ni][r]);
      mx[mi][r] = m;
    }
  #pragma unroll
  for (int msk = 1; msk < 16; msk <<= 1)
    #pragma unroll
    for (int mi = 0; mi < 4; ++mi)
      #pragma unroll
      for (int r = 0; r < 4; ++r)
        mx[mi][r] = fmaxf(mx[mi][r], __shfl_xor(mx[mi][r], msk, 64));
  #pragma unroll
  for (int mi = 0; mi < 4; ++mi)
    #pragma unroll
    for (int r = 0; r < 4; ++r) sm[mi][r] = 0.f;
  #pragma unroll
  for (int mi = 0; mi < 4; ++mi)
    #pragma unroll
    for (int ni = 0; ni < 8; ++ni)
      #pragma unroll
      for (int r = 0; r < 4; ++r) {
        float p = exp2f((s[mi][ni][r] - mx[mi][r]) * SC);
        s[mi][ni][r] = p;
        sm[mi][r] += p;
      }
  #pragma unroll
  for (int msk = 1; msk < 16; msk <<= 1)
    #pragma unroll
    for (int mi = 0; mi < 4; ++mi)
      #pragma unroll
      for (int r = 0; r < 4; ++r)
        sm[mi][r] += __shfl_xor(sm[mi][r], msk, 64);
  #pragma unroll
  for (int mi = 0; mi < 4; ++mi)
    #pragma unroll
    for (int r = 0; r < 4; ++r) rc[mi][r] = __builtin_amdgcn_rcpf(sm[mi][r]);

  // ---- two i-halves: write aT (swizzled), PV against V, accumulate ot ----
  f32x4 ot[2][4] = {};
  #pragma unroll
  for (int hf = 0; hf < 2; ++hf) {
    if ((w >> 1) == hf) {
      #pragma unroll
      for (int mi = 0; mi < 4; ++mi)
        #pragma unroll
        for (int ni = 0; ni < 8; ++ni) {
          s16x4 pk = { f2b(s[mi][ni][0] * rc[mi][0]), f2b(s[mi][ni][1] * rc[mi][1]),
                       f2b(s[mi][ni][2] * rc[mi][2]), f2b(s[mi][ni][3] * rc[mi][3]) };
          int j  = 16 * ni + rl;
          int ci = (w & 1) * 8 + 2 * mi + (q >> 1);
          *(s16x4*)((char*)aT + j * 256 + (ci ^ (j & 7)) * 16 + (q & 1) * 8) = pk;
        }
    }
    __syncthreads();
    #pragma unroll
    for (int kt = 0; kt < 4; ++kt) {
      bf16x8 pa[2], vv[4];
      #pragma unroll
      for (int mi = 0; mi < 2; ++mi) {
        int Rj = 32 * w + 16 * mi + rl;
        int ci = kt * 4 + q;
        pa[mi] = *(const bf16x8*)((const char*)aT + Rj * 256 + (ci ^ (Rj & 7)) * 16);
      }
      int ig = ih * 256 + hf * 128 + kt * 32 + q * 8;
      #pragma unroll
      for (int nd = 0; nd < 4; ++nd)
        vv[nd] = *(const bf16x8*)(&Vb[(long)(16 * nd + rl) * 1024 + ig]);
      #pragma unroll
      for (int mi = 0; mi < 2; ++mi)
        #pragma unroll
        for (int nd = 0; nd < 4; ++nd)
          ot[mi][nd] = MFMA16(pa[mi], vv[nd], ot[mi][nd]);
    }
    __syncthreads();
  }
  // ---- atomic accumulate partial O^T[j][d] (j local to c-chunk) ----
  #pragma unroll
  for (int mi = 0; mi < 2; ++mi)
    #pragma unroll
    for (int nd = 0; nd < 4; ++nd)
      #pragma unroll
      for (int r = 0; r < 4; ++r) {
        int j = c * 128 + 32 * w + 16 * mi + 4 * q + r;
        int d = 16 * nd + rl;
        atomicAdd(&Oz[(long)j * 64 + d], ot[mi][nd][r]);
      }
}

// ---------------- O32 [z][j][d] fp32 -> OTb [b][j][h*64+d] bf16 -------------
__global__ __launch_bounds__(256) void cvt_o(const float* __restrict__ lo,
    const float* __restrict__ hi, short* __restrict__ OT)
{
  int z = blockIdx.y;
  const float* oz = (z < 48) ? lo + (long)z * 65536 : hi + (long)(z - 48) * 65536;
  int b = z >> 3, h = z & 7;
  int off = (blockIdx.x * 256 + threadIdx.x) * 4;
  int j = off >> 6, d = off & 63;
  float4 v = *(const float4*)(oz + off);
  s16x4 s = { f2b(v.x), f2b(v.y), f2b(v.z), f2b(v.w) };
  *(s16x4*)(&OT[((long)b * 1024 + j) * 512 + h * 64 + d]) = s;
}

extern "C" void kernel_launch(void* const* d_in, const int* in_sizes, int n_in,
                              void* d_out, int out_size, void* d_ws, size_t ws_size,
                              hipStream_t stream)
{
  const float* x  = (const float*)d_in[0];
  const float* Wk = (const float*)d_in[1];
  const float* Wq = (const float*)d_in[2];
  const float* Wv = (const float*)d_in[3];
  const float* Wr = (const float*)d_in[4];
  const float* br = (const float*)d_in[5];
  float* out = (float*)d_out;

  char* ws = (char*)d_ws;
  short* Xbf = (short*)(ws + 0);         // [8][256][1024]   dead after M-gemm
  short* XT  = (short*)(ws + 4194304);   // [8][1024][256]   dead after GT/V
  short* WqT = (short*)(ws + 8388608);   // [256][8192]      dead after M-gemm
  short* Wkb = (short*)(ws + 12582912);  // [8192][256]      live through qk_pv
  short* Wvb = (short*)(ws + 16777216);  // [512][256]       dead after V-gemm
  short* Wrb = (short*)(ws + 17039360);  // [256][512]       live to final
  short* Mb  = (short*)(ws + 17301504);  // [8][8][256][256] dead after GT-gemm
  short* GTb = (short*)(ws + 25690112);  // [8][8][1024][256]
  short* Vbf = (short*)(ws + 59244544);  // [8][512][1024]
  short* OTb = (short*)(ws + 67633152);  // [8][1024][512]

  // fp32 O accumulator (16.8 MB) split over dead regions:
  //   z in [0,48):  ws[0 .. 12,582,912)          (Xbf/XT/WqT, dead by then)
  //   z in [48,64): ws[17,301,504 .. 21,495,808) (front of Mb, dead by then)
  float* o32lo = (float*)(ws + 0);
  float* o32hi = (float*)(ws + 17301504);

  // converts / transposes
  tcvt<<<dim3(16, 4, 8), 256, 0, stream>>>(x, Xbf, XT, 256, 1024, 262144L, 262144L, 262144L);
  tcvt<<<dim3(4, 128, 1), 256, 0, stream>>>(Wq, nullptr, WqT, 8192, 256, 0L, 0L, 0L);
  cvt3<<<2304, 256, 0, stream>>>(Wk, Wkb, Wv, Wvb, Wr, Wrb);

  // M[b,h] = X_b @ Wq_h            (256x256, K=1024), BM=64 -> 512 blocks
  gemm_nt<64, false><<<dim3(2, 4, 64), 256, 0, stream>>>(Xbf, WqT, Mb, nullptr,
      256, 256, 1024, 1024, 8192, 256,
      262144L, 0L, 0L, 1024L, 524288L, 65536L, 8);
  // G^T[b,h] = X_b^T @ M           (1024x256, K=256), BM=128 -> 1024 blocks
  gemm_nt<128, false><<<dim3(2, 8, 64), 256, 0, stream>>>(XT, Mb, GTb, nullptr,
      1024, 256, 256, 256, 256, 256,
      262144L, 0L, 524288L, 65536L, 2097152L, 262144L, 8);
  // V[b] = Wv @ X_b                (512x1024, K=256), BM=64 -> 512 blocks
  gemm_nt<64, false><<<dim3(8, 8, 8), 256, 0, stream>>>(Wvb, XT, Vbf, nullptr,
      512, 1024, 256, 256, 256, 1024,
      0L, 0L, 262144L, 0L, 524288L, 0L, 1);

  // zero O32, then one full-width fused attention launch
  zero_o<<<dim3(64, 64), 256, 0, stream>>>(o32lo, o32hi);
  qk_pv<<<2048, 256, 0, stream>>>(Wkb, GTb, Vbf, o32lo, o32hi);
  cvt_o<<<dim3(64, 64), 256, 0, stream>>>(o32lo, o32hi, OTb);

  // Y[b] = Wr @ O_b + br           (256x1024, K=512), BM=64 -> 256 blocks
  gemm_nt<64, true><<<dim3(8, 4, 8), 256, 0, stream>>>(Wrb, OTb, out, br,
      256, 1024, 512, 512, 512, 1024,
      0L, 0L, 524288L, 0L, 262144L, 0L, 1);
}

// Round 8
// 280.660 us; speedup vs baseline: 1.1861x; 1.1191x over previous
//
#include <hip/hip_runtime.h>
#include <hip/hip_bf16.h>

// SignAttention on MI355X, round 8.
// vs r7: qk_pv rebuilt with HALF the accumulator (wave = 32i x 128j, s[2][8]
// = 64 acc regs vs 128). Root cause found: VGPR_Count excludes AGPR acc; all
// prior fused kernels were >256 total regs -> 1 wave/SIMD. Now ~216 total ->
// 2 waves/SIMD, 2 blocks/CU. Grid 4096 (z fastest -> XCD-local L2 reuse).
// PV fused via aT in LDS (32KB alias), fp32 atomicAdd partials.

using bf16x8 = __attribute__((ext_vector_type(8))) __bf16;
using f32x4  = __attribute__((ext_vector_type(4))) float;
using s16x4  = __attribute__((ext_vector_type(4))) short;

static __device__ __forceinline__ short f2b(float f) {  // fp32 -> bf16, RNE
  union { float f; unsigned u; } v; v.f = f;
  unsigned r = v.u + 0x7fffu + ((v.u >> 16) & 1u);
  return (short)(r >> 16);
}

static __device__ __forceinline__ void gll16(const void* g, void* l) {
  __builtin_amdgcn_global_load_lds(
      (const __attribute__((address_space(1))) void*)g,
      (__attribute__((address_space(3))) void*)l, 16, 0, 0);
}

#define MFMA16(a, b, c) __builtin_amdgcn_mfma_f32_16x16x32_bf16((a), (b), (c), 0, 0, 0)

// ---------------- fused fp32->bf16 for Wk|Wv|Wr in one launch ----------------
__global__ __launch_bounds__(256) void cvt3(
    const float* __restrict__ wk, short* __restrict__ wko,
    const float* __restrict__ wv, short* __restrict__ wvo,
    const float* __restrict__ wr, short* __restrict__ wro) {
  int bx = blockIdx.x;
  const float* in; short* out; int base;
  if (bx < 2048)      { in = wk; out = wko; base = bx; }
  else if (bx < 2176) { in = wv; out = wvo; base = bx - 2048; }
  else                { in = wr; out = wro; base = bx - 2176; }
  int i = base * 1024 + threadIdx.x * 4;
  float4 v = *(const float4*)(in + i);
  s16x4 s = { f2b(v.x), f2b(v.y), f2b(v.z), f2b(v.w) };
  *(s16x4*)(out + i) = s;
}

// ------- 64x64-tile convert (+optional plain bf16 copy) + transpose -------
__global__ __launch_bounds__(256) void tcvt(const float* __restrict__ in,
    short* __restrict__ outP, short* __restrict__ outT,
    int R, int C, long inB, long pB, long tB)
{
  __shared__ short tile[64][68];
  long bz = blockIdx.z;
  const float* src = in + bz * inB;
  int r0 = blockIdx.y * 64, c0 = blockIdx.x * 64;
  int t = threadIdx.x;
  int r = t >> 2, cq = (t & 3) * 16;
  #pragma unroll
  for (int e = 0; e < 16; e += 4) {
    float4 v = *(const float4*)(&src[(long)(r0 + r) * C + (c0 + cq + e)]);
    s16x4 s = { f2b(v.x), f2b(v.y), f2b(v.z), f2b(v.w) };
    *(s16x4*)(&tile[r][cq + e]) = s;
    if (outP) *(s16x4*)(&outP[bz * pB + (long)(r0 + r) * C + (c0 + cq + e)]) = s;
  }
  __syncthreads();
  int tr = t >> 2, re = (t & 3) * 16;
  short tmp[16];
  #pragma unroll
  for (int e = 0; e < 16; ++e) tmp[e] = tile[re + e][tr];
  short* dst = &outT[bz * tB + (long)(c0 + tr) * R + (r0 + re)];
  #pragma unroll
  for (int e = 0; e < 16; e += 4) *(s16x4*)(&dst[e]) = *(const s16x4*)(&tmp[e]);
}

// ---------------- generic batched NT GEMM, m97 structure, BM templated ------
template<int BM, bool F32OUT>
__global__ __launch_bounds__(256) void gemm_nt(
    const short* __restrict__ A, const short* __restrict__ B,
    void* __restrict__ C, const float* __restrict__ bias,
    int M, int N, int K, int lda, int ldb, int ldc,
    long aSB, long aSH, long bSB, long bSH, long cSB, long cSH, int nh)
{
  constexpr int MI = BM / 32;       // A fragments per wave
  int batch = blockIdx.z;
  int hb = batch % nh, bb = batch / nh;
  const short* Ab = A + bb * aSB + hb * aSH;
  const short* Bb = B + bb * bSB + hb * bSH;
  long cOff = bb * cSB + hb * cSH;
  int m0 = blockIdx.y * BM, n0 = blockIdx.x * 128;
  __shared__ short As[BM * 64];
  __shared__ short Bs[128 * 64];
  int t = threadIdx.x;
  int lane = t & 63, wid = t >> 6;
  int wm = (wid >> 1) * (BM / 2), wn = (wid & 1) * 64;
  int rl = lane & 15, q = lane >> 4;
  f32x4 acc[MI][4] = {};
  for (int k0 = 0; k0 < K; k0 += 64) {
    __syncthreads();
    #pragma unroll
    for (int j = 0; j < BM / 32; ++j) {
      int g = j * 256 + t;
      int r = g >> 3, cc = g & 7;
      int cs = cc ^ (r & 7);
      gll16(&Ab[(long)(m0 + r) * lda + k0 + cs * 8], (char*)As + (j * 256 + wid * 64) * 16);
    }
    #pragma unroll
    for (int j = 0; j < 4; ++j) {
      int g = j * 256 + t;
      int r = g >> 3, cc = g & 7;
      int cs = cc ^ (r & 7);
      gll16(&Bb[(long)(n0 + r) * ldb + k0 + cs * 8], (char*)Bs + (j * 256 + wid * 64) * 16);
    }
    __syncthreads();
    #pragma unroll
    for (int kt = 0; kt < 2; ++kt) {
      int cq = kt * 4 + q;
      bf16x8 af[MI], bfv[4];
      #pragma unroll
      for (int mi = 0; mi < MI; ++mi) {
        int R = wm + 16 * mi + rl;
        af[mi] = *(const bf16x8*)((const char*)As + (R * 8 + (cq ^ (R & 7))) * 16);
      }
      #pragma unroll
      for (int ni = 0; ni < 4; ++ni) {
        int RN = wn + 16 * ni + rl;
        bfv[ni] = *(const bf16x8*)((const char*)Bs + (RN * 8 + (cq ^ (RN & 7))) * 16);
      }
      #pragma unroll
      for (int mi = 0; mi < MI; ++mi)
        #pragma unroll
        for (int ni = 0; ni < 4; ++ni)
          acc[mi][ni] = MFMA16(af[mi], bfv[ni], acc[mi][ni]);
    }
  }
  #pragma unroll
  for (int mi = 0; mi < MI; ++mi)
    #pragma unroll
    for (int ni = 0; ni < 4; ++ni)
      #pragma unroll
      for (int r = 0; r < 4; ++r) {
        int row = m0 + wm + 16 * mi + 4 * q + r;
        int col = n0 + wn + 16 * ni + rl;
        float val = acc[mi][ni][r];
        if (F32OUT) {
          ((float*)C)[cOff + (long)row * ldc + col] = val + (bias ? bias[row] : 0.f);
        } else {
          ((short*)C)[cOff + (long)row * ldc + col] = f2b(val);
        }
      }
}

// ---------------- zero the fp32 O accumulator (split placement) -------------
__global__ __launch_bounds__(256) void zero_o(float* __restrict__ lo,
                                              float* __restrict__ hi) {
  int z = blockIdx.y;
  float* oz = (z < 48) ? lo + (long)z * 65536 : hi + (long)(z - 48) * 65536;
  int idx = (blockIdx.x * 256 + threadIdx.x) * 4;
  float4 zz = {0.f, 0.f, 0.f, 0.f};
  *(float4*)(oz + idx) = zz;
}

// ---- qk_pv: S = Wk[it-slab 128i] @ G[c-chunk 128j]; chunk-softmax;
// ---- PV partial over the 128-i window; fp32 atomicAdd into O32[z][j][d].
// ---- grid dim3(z=64, it=8, c=8): flattened id%8 = z%8 -> XCD-local L2 sets.
// ---- Wave = 32i x 128j: s[2][8] = 64 acc regs (the r8 occupancy fix).
__global__ __launch_bounds__(256) void qk_pv(
    const short* __restrict__ Wk, const short* __restrict__ GT,
    const short* __restrict__ V, float* __restrict__ o32lo,
    float* __restrict__ o32hi)
{
  __shared__ short smem[16384];  // 32 KiB: As[128][64] | Bs[128][64]
  short* As = smem;
  short* Bs = smem + 8192;
  short* aT = smem;              // [128 j][128 i], aliases As|Bs after QK
  int z = blockIdx.x, it = blockIdx.y, c = blockIdx.z;
  int b = z >> 3, h = z & 7;
  int t = threadIdx.x, lane = t & 63, w = t >> 6;
  int rl = lane & 15, q = lane >> 4;
  const short* Ab = Wk + (long)(h * 1024 + it * 128) * 256;
  const short* Bb = GT + ((long)z * 1024 + c * 128) * 256;
  const short* Vb = V + (long)(b * 512 + h * 64) * 1024;
  float* Oz = (z < 48) ? o32lo + (long)z * 65536 : o32hi + (long)(z - 48) * 65536;
  const float SC = 1.4426950408889634f / 32.0f;  // log2(e)/sqrt(dk)

  // ---- QK: S[128 i][128 j], K=256 in 4 steps ----
  f32x4 s[2][8] = {};
  for (int k0 = 0; k0 < 256; k0 += 64) {
    __syncthreads();
    #pragma unroll
    for (int j = 0; j < 4; ++j) {
      int g = j * 256 + t;
      int r = g >> 3, cc = g & 7, cs = cc ^ (r & 7);
      gll16(&Ab[(long)r * 256 + k0 + cs * 8], (char*)As + (j * 256 + w * 64) * 16);
      gll16(&Bb[(long)r * 256 + k0 + cs * 8], (char*)Bs + (j * 256 + w * 64) * 16);
    }
    __syncthreads();
    #pragma unroll
    for (int kt = 0; kt < 2; ++kt) {
      int cq = kt * 4 + q;
      bf16x8 af[2];
      #pragma unroll
      for (int mi = 0; mi < 2; ++mi) {
        int R = 32 * w + 16 * mi + rl;
        af[mi] = *(const bf16x8*)((const char*)As + (R * 8 + (cq ^ (R & 7))) * 16);
      }
      #pragma unroll
      for (int ni = 0; ni < 8; ++ni) {
        int RN = 16 * ni + rl;
        bf16x8 bv = *(const bf16x8*)((const char*)Bs + (RN * 8 + (cq ^ (RN & 7))) * 16);
        #pragma unroll
        for (int mi = 0; mi < 2; ++mi)
          s[mi][ni] = MFMA16(af[mi], bv, s[mi][ni]);
      }
    }
  }
  __syncthreads();  // all QK LDS reads done before aT alias reuse

  // ---- softmax over 128 j per row (row = 32w+16mi+4q+r) ----
  float mx[2][4], sm[2][4], rc[2][4];
  #pragma unroll
  for (int mi = 0; mi < 2; ++mi)
    #pragma unroll
    for (int r = 0; r < 4; ++r) {
      float m = s[mi][0][r];
      #pragma unroll
      for (int ni = 1; ni < 8; ++ni) m = fmaxf(m, s[mi][ni][r]);
      mx[mi][r] = m;
    }
  #pragma unroll
  for (int msk = 1; msk < 16; msk <<= 1)
    #pragma unroll
    for (int mi = 0; mi < 2; ++mi)
      #pragma unroll
      for (int r = 0; r < 4; ++r)
        mx[mi][r] = fmaxf(mx[mi][r], __shfl_xor(mx[mi][r], msk, 64));
  #pragma unroll
  for (int mi = 0; mi < 2; ++mi)
    #pragma unroll
    for (int r = 0; r < 4; ++r) sm[mi][r] = 0.f;
  #pragma unroll
  for (int mi = 0; mi < 2; ++mi)
    #pragma unroll
    for (int ni = 0; ni < 8; ++ni)
      #pragma unroll
      for (int r = 0; r < 4; ++r) {
        float p = exp2f((s[mi][ni][r] - mx[mi][r]) * SC);
        s[mi][ni][r] = p;
        sm[mi][r] += p;
      }
  #pragma unroll
  for (int msk = 1; msk < 16; msk <<= 1)
    #pragma unroll
    for (int mi = 0; mi < 2; ++mi)
      #pragma unroll
      for (int r = 0; r < 4; ++r)
        sm[mi][r] += __shfl_xor(sm[mi][r], msk, 64);
  #pragma unroll
  for (int mi = 0; mi < 2; ++mi)
    #pragma unroll
    for (int r = 0; r < 4; ++r) rc[mi][r] = __builtin_amdgcn_rcpf(sm[mi][r]);

  // ---- write attn^T into aT (swizzled): aT[j][i_loc], i_loc = 32w+16mi+4q+r
  #pragma unroll
  for (int mi = 0; mi < 2; ++mi)
    #pragma unroll
    for (int ni = 0; ni < 8; ++ni) {
      s16x4 pk = { f2b(s[mi][ni][0] * rc[mi][0]), f2b(s[mi][ni][1] * rc[mi][1]),
                   f2b(s[mi][ni][2] * rc[mi][2]), f2b(s[mi][ni][3] * rc[mi][3]) };
      int j  = 16 * ni + rl;
      int ci = 4 * w + 2 * mi + (q >> 1);
      *(s16x4*)((char*)aT + j * 256 + (ci ^ (j & 7)) * 16 + (q & 1) * 8) = pk;
    }
  __syncthreads();

  // ---- PV: wave w owns j rows 32w..32w+31; O[j][d] += attn^T[j][:].V^T[:][d]
  f32x4 ot[2][4] = {};
  #pragma unroll
  for (int kt = 0; kt < 4; ++kt) {
    bf16x8 pa[2], vv[4];
    #pragma unroll
    for (int mi = 0; mi < 2; ++mi) {
      int Rj = 32 * w + 16 * mi + rl;
      int ci = kt * 4 + q;
      pa[mi] = *(const bf16x8*)((const char*)aT + Rj * 256 + (ci ^ (Rj & 7)) * 16);
    }
    int ig = it * 128 + kt * 32 + q * 8;
    #pragma unroll
    for (int nd = 0; nd < 4; ++nd)
      vv[nd] = *(const bf16x8*)(&Vb[(long)(16 * nd + rl) * 1024 + ig]);
    #pragma unroll
    for (int mi = 0; mi < 2; ++mi)
      #pragma unroll
      for (int nd = 0; nd < 4; ++nd)
        ot[mi][nd] = MFMA16(pa[mi], vv[nd], ot[mi][nd]);
  }
  // ---- atomic accumulate partial O^T[j][d] ----
  #pragma unroll
  for (int mi = 0; mi < 2; ++mi)
    #pragma unroll
    for (int nd = 0; nd < 4; ++nd)
      #pragma unroll
      for (int r = 0; r < 4; ++r) {
        int j = c * 128 + 32 * w + 16 * mi + 4 * q + r;
        int d = 16 * nd + rl;
        atomicAdd(&Oz[(long)j * 64 + d], ot[mi][nd][r]);
      }
}

// ---------------- O32 [z][j][d] fp32 -> OTb [b][j][h*64+d] bf16 -------------
__global__ __launch_bounds__(256) void cvt_o(const float* __restrict__ lo,
    const float* __restrict__ hi, short* __restrict__ OT)
{
  int z = blockIdx.y;
  const float* oz = (z < 48) ? lo + (long)z * 65536 : hi + (long)(z - 48) * 65536;
  int b = z >> 3, h = z & 7;
  int off = (blockIdx.x * 256 + threadIdx.x) * 4;
  int j = off >> 6, d = off & 63;
  float4 v = *(const float4*)(oz + off);
  s16x4 s = { f2b(v.x), f2b(v.y), f2b(v.z), f2b(v.w) };
  *(s16x4*)(&OT[((long)b * 1024 + j) * 512 + h * 64 + d]) = s;
}

extern "C" void kernel_launch(void* const* d_in, const int* in_sizes, int n_in,
                              void* d_out, int out_size, void* d_ws, size_t ws_size,
                              hipStream_t stream)
{
  const float* x  = (const float*)d_in[0];
  const float* Wk = (const float*)d_in[1];
  const float* Wq = (const float*)d_in[2];
  const float* Wv = (const float*)d_in[3];
  const float* Wr = (const float*)d_in[4];
  const float* br = (const float*)d_in[5];
  float* out = (float*)d_out;

  char* ws = (char*)d_ws;
  short* Xbf = (short*)(ws + 0);         // [8][256][1024]   dead after M-gemm
  short* XT  = (short*)(ws + 4194304);   // [8][1024][256]   dead after GT/V
  short* WqT = (short*)(ws + 8388608);   // [256][8192]      dead after M-gemm
  short* Wkb = (short*)(ws + 12582912);  // [8192][256]      live through qk_pv
  short* Wvb = (short*)(ws + 16777216);  // [512][256]       dead after V-gemm
  short* Wrb = (short*)(ws + 17039360);  // [256][512]       live to final
  short* Mb  = (short*)(ws + 17301504);  // [8][8][256][256] dead after GT-gemm
  short* GTb = (short*)(ws + 25690112);  // [8][8][1024][256]
  short* Vbf = (short*)(ws + 59244544);  // [8][512][1024]
  short* OTb = (short*)(ws + 67633152);  // [8][1024][512]

  // fp32 O accumulator (16.8 MB) split over dead regions:
  //   z in [0,48):  ws[0 .. 12,582,912)          (Xbf/XT/WqT, dead by then)
  //   z in [48,64): ws[17,301,504 .. 21,495,808) (front of Mb, dead by then)
  float* o32lo = (float*)(ws + 0);
  float* o32hi = (float*)(ws + 17301504);

  // converts / transposes
  tcvt<<<dim3(16, 4, 8), 256, 0, stream>>>(x, Xbf, XT, 256, 1024, 262144L, 262144L, 262144L);
  tcvt<<<dim3(4, 128, 1), 256, 0, stream>>>(Wq, nullptr, WqT, 8192, 256, 0L, 0L, 0L);
  cvt3<<<2304, 256, 0, stream>>>(Wk, Wkb, Wv, Wvb, Wr, Wrb);

  // M[b,h] = X_b @ Wq_h            (256x256, K=1024), BM=64 -> 512 blocks
  gemm_nt<64, false><<<dim3(2, 4, 64), 256, 0, stream>>>(Xbf, WqT, Mb, nullptr,
      256, 256, 1024, 1024, 8192, 256,
      262144L, 0L, 0L, 1024L, 524288L, 65536L, 8);
  // G^T[b,h] = X_b^T @ M           (1024x256, K=256), BM=128 -> 1024 blocks
  gemm_nt<128, false><<<dim3(2, 8, 64), 256, 0, stream>>>(XT, Mb, GTb, nullptr,
      1024, 256, 256, 256, 256, 256,
      262144L, 0L, 524288L, 65536L, 2097152L, 262144L, 8);
  // V[b] = Wv @ X_b                (512x1024, K=256), BM=64 -> 512 blocks
  gemm_nt<64, false><<<dim3(8, 8, 8), 256, 0, stream>>>(Wvb, XT, Vbf, nullptr,
      512, 1024, 256, 256, 256, 1024,
      0L, 0L, 262144L, 0L, 524288L, 0L, 1);

  // zero O32, then one full-width fused attention launch
  zero_o<<<dim3(64, 64), 256, 0, stream>>>(o32lo, o32hi);
  qk_pv<<<dim3(64, 8, 8), 256, 0, stream>>>(Wkb, GTb, Vbf, o32lo, o32hi);
  cvt_o<<<dim3(64, 64), 256, 0, stream>>>(o32lo, o32hi, OTb);

  // Y[b] = Wr @ O_b + br           (256x1024, K=512), BM=64 -> 256 blocks
  gemm_nt<64, true><<<dim3(8, 4, 8), 256, 0, stream>>>(Wrb, OTb, out, br,
      256, 1024, 512, 512, 512, 1024,
      0L, 0L, 524288L, 0L, 262144L, 0L, 1);
}

// Round 12
// 279.704 us; speedup vs baseline: 1.1902x; 1.0034x over previous
//
#include <hip/hip_runtime.h>
#include <hip/hip_bf16.h>

// SignAttention on MI355X, round 12 (= round-9 kernel, fourth submission;
// r9 container failure, r10/r11 acquisition timeouts — never executed).
// vs r8: T3-minimum 2-phase prefetch in qk_pv and gemm_nt — stage K-slab t+1
// BEFORE computing slab t (double-buffered LDS), ONE barrier per K-step.
// Load latency hides under MFMA instead of being exposed at a vmcnt(0) drain
// right after issue. qk_pv LDS 32->64KB (2 blocks/CU), gemm BM=64 48KB
// (3 blocks/CU). Everything else identical to the passing r8.

using bf16x8 = __attribute__((ext_vector_type(8))) __bf16;
using f32x4  = __attribute__((ext_vector_type(4))) float;
using s16x4  = __attribute__((ext_vector_type(4))) short;

static __device__ __forceinline__ short f2b(float f) {  // fp32 -> bf16, RNE
  union { float f; unsigned u; } v; v.f = f;
  unsigned r = v.u + 0x7fffu + ((v.u >> 16) & 1u);
  return (short)(r >> 16);
}

static __device__ __forceinline__ void gll16(const void* g, void* l) {
  __builtin_amdgcn_global_load_lds(
      (const __attribute__((address_space(1))) void*)g,
      (__attribute__((address_space(3))) void*)l, 16, 0, 0);
}

#define MFMA16(a, b, c) __builtin_amdgcn_mfma_f32_16x16x32_bf16((a), (b), (c), 0, 0, 0)

// ---------------- fused fp32->bf16 for Wk|Wv|Wr in one launch ----------------
__global__ __launch_bounds__(256) void cvt3(
    const float* __restrict__ wk, short* __restrict__ wko,
    const float* __restrict__ wv, short* __restrict__ wvo,
    const float* __restrict__ wr, short* __restrict__ wro) {
  int bx = blockIdx.x;
  const float* in; short* out; int base;
  if (bx < 2048)      { in = wk; out = wko; base = bx; }
  else if (bx < 2176) { in = wv; out = wvo; base = bx - 2048; }
  else                { in = wr; out = wro; base = bx - 2176; }
  int i = base * 1024 + threadIdx.x * 4;
  float4 v = *(const float4*)(in + i);
  s16x4 s = { f2b(v.x), f2b(v.y), f2b(v.z), f2b(v.w) };
  *(s16x4*)(out + i) = s;
}

// ------- 64x64-tile convert (+optional plain bf16 copy) + transpose -------
__global__ __launch_bounds__(256) void tcvt(const float* __restrict__ in,
    short* __restrict__ outP, short* __restrict__ outT,
    int R, int C, long inB, long pB, long tB)
{
  __shared__ short tile[64][68];
  long bz = blockIdx.z;
  const float* src = in + bz * inB;
  int r0 = blockIdx.y * 64, c0 = blockIdx.x * 64;
  int t = threadIdx.x;
  int r = t >> 2, cq = (t & 3) * 16;
  #pragma unroll
  for (int e = 0; e < 16; e += 4) {
    float4 v = *(const float4*)(&src[(long)(r0 + r) * C + (c0 + cq + e)]);
    s16x4 s = { f2b(v.x), f2b(v.y), f2b(v.z), f2b(v.w) };
    *(s16x4*)(&tile[r][cq + e]) = s;
    if (outP) *(s16x4*)(&outP[bz * pB + (long)(r0 + r) * C + (c0 + cq + e)]) = s;
  }
  __syncthreads();
  int tr = t >> 2, re = (t & 3) * 16;
  short tmp[16];
  #pragma unroll
  for (int e = 0; e < 16; ++e) tmp[e] = tile[re + e][tr];
  short* dst = &outT[bz * tB + (long)(c0 + tr) * R + (r0 + re)];
  #pragma unroll
  for (int e = 0; e < 16; e += 4) *(s16x4*)(&dst[e]) = *(const s16x4*)(&tmp[e]);
}

// -------- generic batched NT GEMM, m97 staging + 2-phase prefetch dbuf ------
template<int BM, bool F32OUT>
__global__ __launch_bounds__(256) void gemm_nt(
    const short* __restrict__ A, const short* __restrict__ B,
    void* __restrict__ C, const float* __restrict__ bias,
    int M, int N, int K, int lda, int ldb, int ldc,
    long aSB, long aSH, long bSB, long bSH, long cSB, long cSH, int nh)
{
  constexpr int MI = BM / 32;       // A fragments per wave
  int batch = blockIdx.z;
  int hb = batch % nh, bb = batch / nh;
  const short* Ab = A + bb * aSB + hb * aSH;
  const short* Bb = B + bb * bSB + hb * bSH;
  long cOff = bb * cSB + hb * cSH;
  int m0 = blockIdx.y * BM, n0 = blockIdx.x * 128;
  __shared__ short As[2][BM * 64];
  __shared__ short Bs[2][128 * 64];
  int t = threadIdx.x;
  int lane = t & 63, wid = t >> 6;
  int wm = (wid >> 1) * (BM / 2), wn = (wid & 1) * 64;
  int rl = lane & 15, q = lane >> 4;

  auto stage = [&](short* dA, short* dB, int k0) {
    #pragma unroll
    for (int j = 0; j < BM / 32; ++j) {
      int g = j * 256 + t;
      int r = g >> 3, cc = g & 7, cs = cc ^ (r & 7);
      gll16(&Ab[(long)(m0 + r) * lda + k0 + cs * 8], (char*)dA + (j * 256 + wid * 64) * 16);
    }
    #pragma unroll
    for (int j = 0; j < 4; ++j) {
      int g = j * 256 + t;
      int r = g >> 3, cc = g & 7, cs = cc ^ (r & 7);
      gll16(&Bb[(long)(n0 + r) * ldb + k0 + cs * 8], (char*)dB + (j * 256 + wid * 64) * 16);
    }
  };

  f32x4 acc[MI][4] = {};
  stage(As[0], Bs[0], 0);
  __syncthreads();
  int cur = 0;
  for (int k0 = 0; k0 < K; k0 += 64) {
    if (k0 + 64 < K) stage(As[cur ^ 1], Bs[cur ^ 1], k0 + 64);
    const char* Ac = (const char*)As[cur];
    const char* Bc = (const char*)Bs[cur];
    #pragma unroll
    for (int kt = 0; kt < 2; ++kt) {
      int cq = kt * 4 + q;
      bf16x8 af[MI], bfv[4];
      #pragma unroll
      for (int mi = 0; mi < MI; ++mi) {
        int R = wm + 16 * mi + rl;
        af[mi] = *(const bf16x8*)(Ac + (R * 8 + (cq ^ (R & 7))) * 16);
      }
      #pragma unroll
      for (int ni = 0; ni < 4; ++ni) {
        int RN = wn + 16 * ni + rl;
        bfv[ni] = *(const bf16x8*)(Bc + (RN * 8 + (cq ^ (RN & 7))) * 16);
      }
      #pragma unroll
      for (int mi = 0; mi < MI; ++mi)
        #pragma unroll
        for (int ni = 0; ni < 4; ++ni)
          acc[mi][ni] = MFMA16(af[mi], bfv[ni], acc[mi][ni]);
    }
    __syncthreads();   // drains vmcnt (next buf ready) + readers done with cur
    cur ^= 1;
  }
  #pragma unroll
  for (int mi = 0; mi < MI; ++mi)
    #pragma unroll
    for (int ni = 0; ni < 4; ++ni)
      #pragma unroll
      for (int r = 0; r < 4; ++r) {
        int row = m0 + wm + 16 * mi + 4 * q + r;
        int col = n0 + wn + 16 * ni + rl;
        float val = acc[mi][ni][r];
        if (F32OUT) {
          ((float*)C)[cOff + (long)row * ldc + col] = val + (bias ? bias[row] : 0.f);
        } else {
          ((short*)C)[cOff + (long)row * ldc + col] = f2b(val);
        }
      }
}

// ---------------- zero the fp32 O accumulator (split placement) -------------
__global__ __launch_bounds__(256) void zero_o(float* __restrict__ lo,
                                              float* __restrict__ hi) {
  int z = blockIdx.y;
  float* oz = (z < 48) ? lo + (long)z * 65536 : hi + (long)(z - 48) * 65536;
  int idx = (blockIdx.x * 256 + threadIdx.x) * 4;
  float4 zz = {0.f, 0.f, 0.f, 0.f};
  *(float4*)(oz + idx) = zz;
}

// ---- qk_pv: S = Wk[it-slab 128i] @ G[c-chunk 128j]; chunk-softmax; PV;
// ---- fp32 atomicAdd partials. 2-phase prefetch K-loop (dbuf As/Bs, 64KB).
__global__ __launch_bounds__(256) void qk_pv(
    const short* __restrict__ Wk, const short* __restrict__ GT,
    const short* __restrict__ V, float* __restrict__ o32lo,
    float* __restrict__ o32hi)
{
  __shared__ short smem[32768];           // 64 KiB
  short* As0 = smem;                      // [128][64] each
  short* As1 = smem + 8192;
  short* Bs0 = smem + 16384;
  short* Bs1 = smem + 24576;
  short* aT  = smem;                      // [128 j][128 i] over As0|As1 (32KB)
  int z = blockIdx.x, it = blockIdx.y, c = blockIdx.z;
  int b = z >> 3, h = z & 7;
  int t = threadIdx.x, lane = t & 63, w = t >> 6;
  int rl = lane & 15, q = lane >> 4;
  const short* Ab = Wk + (long)(h * 1024 + it * 128) * 256;
  const short* Bb = GT + ((long)z * 1024 + c * 128) * 256;
  const short* Vb = V + (long)(b * 512 + h * 64) * 1024;
  float* Oz = (z < 48) ? o32lo + (long)z * 65536 : o32hi + (long)(z - 48) * 65536;
  const float SC = 1.4426950408889634f / 32.0f;  // log2(e)/sqrt(dk)

  auto stage = [&](short* dA, short* dB, int k0) {
    #pragma unroll
    for (int j = 0; j < 4; ++j) {
      int g = j * 256 + t;
      int r = g >> 3, cc = g & 7, cs = cc ^ (r & 7);
      gll16(&Ab[(long)r * 256 + k0 + cs * 8], (char*)dA + (j * 256 + w * 64) * 16);
      gll16(&Bb[(long)r * 256 + k0 + cs * 8], (char*)dB + (j * 256 + w * 64) * 16);
    }
  };

  // ---- QK: S[128 i][128 j], K=256 in 4 prefetched steps ----
  f32x4 s[2][8] = {};
  stage(As0, Bs0, 0);
  __syncthreads();
  #pragma unroll
  for (int ks = 0; ks < 4; ++ks) {
    const char* Ac = (const char*)((ks & 1) ? As1 : As0);
    const char* Bc = (const char*)((ks & 1) ? Bs1 : Bs0);
    if (ks < 3) stage((ks & 1) ? As0 : As1, (ks & 1) ? Bs0 : Bs1, (ks + 1) * 64);
    #pragma unroll
    for (int kt = 0; kt < 2; ++kt) {
      int cq = kt * 4 + q;
      bf16x8 af[2];
      #pragma unroll
      for (int mi = 0; mi < 2; ++mi) {
        int R = 32 * w + 16 * mi + rl;
        af[mi] = *(const bf16x8*)(Ac + (R * 8 + (cq ^ (R & 7))) * 16);
      }
      #pragma unroll
      for (int ni = 0; ni < 8; ++ni) {
        int RN = 16 * ni + rl;
        bf16x8 bv = *(const bf16x8*)(Bc + (RN * 8 + (cq ^ (RN & 7))) * 16);
        #pragma unroll
        for (int mi = 0; mi < 2; ++mi)
          s[mi][ni] = MFMA16(af[mi], bv, s[mi][ni]);
      }
    }
    __syncthreads();  // next buf staged+drained; readers done with cur
  }

  // ---- softmax over 128 j per row (row = 32w+16mi+4q+r) ----
  float mx[2][4], sm[2][4], rc[2][4];
  #pragma unroll
  for (int mi = 0; mi < 2; ++mi)
    #pragma unroll
    for (int r = 0; r < 4; ++r) {
      float m = s[mi][0][r];
      #pragma unroll
      for (int ni = 1; ni < 8; ++ni) m = fmaxf(m, s[mi][ni][r]);
      mx[mi][r] = m;
    }
  #pragma unroll
  for (int msk = 1; msk < 16; msk <<= 1)
    #pragma unroll
    for (int mi = 0; mi < 2; ++mi)
      #pragma unroll
      for (int r = 0; r < 4; ++r)
        mx[mi][r] = fmaxf(mx[mi][r], __shfl_xor(mx[mi][r], msk, 64));
  #pragma unroll
  for (int mi = 0; mi < 2; ++mi)
    #pragma unroll
    for (int r = 0; r < 4; ++r) sm[mi][r] = 0.f;
  #pragma unroll
  for (int mi = 0; mi < 2; ++mi)
    #pragma unroll
    for (int ni = 0; ni < 8; ++ni)
      #pragma unroll
      for (int r = 0; r < 4; ++r) {
        float p = exp2f((s[mi][ni][r] - mx[mi][r]) * SC);
        s[mi][ni][r] = p;
        sm[mi][r] += p;
      }
  #pragma unroll
  for (int msk = 1; msk < 16; msk <<= 1)
    #pragma unroll
    for (int mi = 0; mi < 2; ++mi)
      #pragma unroll
      for (int r = 0; r < 4; ++r)
        sm[mi][r] += __shfl_xor(sm[mi][r], msk, 64);
  #pragma unroll
  for (int mi = 0; mi < 2; ++mi)
    #pragma unroll
    for (int r = 0; r < 4; ++r) rc[mi][r] = __builtin_amdgcn_rcpf(sm[mi][r]);

  // ---- write attn^T into aT (swizzled): aT[j][i_loc], i_loc = 32w+16mi+4q+r
  #pragma unroll
  for (int mi = 0; mi < 2; ++mi)
    #pragma unroll
    for (int ni = 0; ni < 8; ++ni) {
      s16x4 pk = { f2b(s[mi][ni][0] * rc[mi][0]), f2b(s[mi][ni][1] * rc[mi][1]),
                   f2b(s[mi][ni][2] * rc[mi][2]), f2b(s[mi][ni][3] * rc[mi][3]) };
      int j  = 16 * ni + rl;
      int ci = 4 * w + 2 * mi + (q >> 1);
      *(s16x4*)((char*)aT + j * 256 + (ci ^ (j & 7)) * 16 + (q & 1) * 8) = pk;
    }
  __syncthreads();

  // ---- PV: wave w owns j rows 32w..32w+31; O[j][d] += attn^T[j][:].V^T[:][d]
  f32x4 ot[2][4] = {};
  #pragma unroll
  for (int kt = 0; kt < 4; ++kt) {
    bf16x8 pa[2], vv[4];
    #pragma unroll
    for (int mi = 0; mi < 2; ++mi) {
      int Rj = 32 * w + 16 * mi + rl;
      int ci = kt * 4 + q;
      pa[mi] = *(const bf16x8*)((const char*)aT + Rj * 256 + (ci ^ (Rj & 7)) * 16);
    }
    int ig = it * 128 + kt * 32 + q * 8;
    #pragma unroll
    for (int nd = 0; nd < 4; ++nd)
      vv[nd] = *(const bf16x8*)(&Vb[(long)(16 * nd + rl) * 1024 + ig]);
    #pragma unroll
    for (int mi = 0; mi < 2; ++mi)
      #pragma unroll
      for (int nd = 0; nd < 4; ++nd)
        ot[mi][nd] = MFMA16(pa[mi], vv[nd], ot[mi][nd]);
  }
  // ---- atomic accumulate partial O^T[j][d] ----
  #pragma unroll
  for (int mi = 0; mi < 2; ++mi)
    #pragma unroll
    for (int nd = 0; nd < 4; ++nd)
      #pragma unroll
      for (int r = 0; r < 4; ++r) {
        int j = c * 128 + 32 * w + 16 * mi + 4 * q + r;
        int d = 16 * nd + rl;
        atomicAdd(&Oz[(long)j * 64 + d], ot[mi][nd][r]);
      }
}

// ---------------- O32 [z][j][d] fp32 -> OTb [b][j][h*64+d] bf16 -------------
__global__ __launch_bounds__(256) void cvt_o(const float* __restrict__ lo,
    const float* __restrict__ hi, short* __restrict__ OT)
{
  int z = blockIdx.y;
  const float* oz = (z < 48) ? lo + (long)z * 65536 : hi + (long)(z - 48) * 65536;
  int b = z >> 3, h = z & 7;
  int off = (blockIdx.x * 256 + threadIdx.x) * 4;
  int j = off >> 6, d = off & 63;
  float4 v = *(const float4*)(oz + off);
  s16x4 s = { f2b(v.x), f2b(v.y), f2b(v.z), f2b(v.w) };
  *(s16x4*)(&OT[((long)b * 1024 + j) * 512 + h * 64 + d]) = s;
}

extern "C" void kernel_launch(void* const* d_in, const int* in_sizes, int n_in,
                              void* d_out, int out_size, void* d_ws, size_t ws_size,
                              hipStream_t stream)
{
  const float* x  = (const float*)d_in[0];
  const float* Wk = (const float*)d_in[1];
  const float* Wq = (const float*)d_in[2];
  const float* Wv = (const float*)d_in[3];
  const float* Wr = (const float*)d_in[4];
  const float* br = (const float*)d_in[5];
  float* out = (float*)d_out;

  char* ws = (char*)d_ws;
  short* Xbf = (short*)(ws + 0);         // [8][256][1024]   dead after M-gemm
  short* XT  = (short*)(ws + 4194304);   // [8][1024][256]   dead after GT/V
  short* WqT = (short*)(ws + 8388608);   // [256][8192]      dead after M-gemm
  short* Wkb = (short*)(ws + 12582912);  // [8192][256]      live through qk_pv
  short* Wvb = (short*)(ws + 16777216);  // [512][256]       dead after V-gemm
  short* Wrb = (short*)(ws + 17039360);  // [256][512]       live to final
  short* Mb  = (short*)(ws + 17301504);  // [8][8][256][256] dead after GT-gemm
  short* GTb = (short*)(ws + 25690112);  // [8][8][1024][256]
  short* Vbf = (short*)(ws + 59244544);  // [8][512][1024]
  short* OTb = (short*)(ws + 67633152);  // [8][1024][512]

  // fp32 O accumulator (16.8 MB) split over dead regions:
  //   z in [0,48):  ws[0 .. 12,582,912)          (Xbf/XT/WqT, dead by then)
  //   z in [48,64): ws[17,301,504 .. 21,495,808) (front of Mb, dead by then)
  float* o32lo = (float*)(ws + 0);
  float* o32hi = (float*)(ws + 17301504);

  // converts / transposes
  tcvt<<<dim3(16, 4, 8), 256, 0, stream>>>(x, Xbf, XT, 256, 1024, 262144L, 262144L, 262144L);
  tcvt<<<dim3(4, 128, 1), 256, 0, stream>>>(Wq, nullptr, WqT, 8192, 256, 0L, 0L, 0L);
  cvt3<<<2304, 256, 0, stream>>>(Wk, Wkb, Wv, Wvb, Wr, Wrb);

  // M[b,h] = X_b @ Wq_h            (256x256, K=1024), BM=64 -> 512 blocks
  gemm_nt<64, false><<<dim3(2, 4, 64), 256, 0, stream>>>(Xbf, WqT, Mb, nullptr,
      256, 256, 1024, 1024, 8192, 256,
      262144L, 0L, 0L, 1024L, 524288L, 65536L, 8);
  // G^T[b,h] = X_b^T @ M           (1024x256, K=256), BM=128 -> 1024 blocks
  gemm_nt<128, false><<<dim3(2, 8, 64), 256, 0, stream>>>(XT, Mb, GTb, nullptr,
      1024, 256, 256, 256, 256, 256,
      262144L, 0L, 524288L, 65536L, 2097152L, 262144L, 8);
  // V[b] = Wv @ X_b                (512x1024, K=256), BM=64 -> 512 blocks
  gemm_nt<64, false><<<dim3(8, 8, 8), 256, 0, stream>>>(Wvb, XT, Vbf, nullptr,
      512, 1024, 256, 256, 256, 1024,
      0L, 0L, 262144L, 0L, 524288L, 0L, 1);

  // zero O32, then one full-width fused attention launch
  zero_o<<<dim3(64, 64), 256, 0, stream>>>(o32lo, o32hi);
  qk_pv<<<dim3(64, 8, 8), 256, 0, stream>>>(Wkb, GTb, Vbf, o32lo, o32hi);
  cvt_o<<<dim3(64, 64), 256, 0, stream>>>(o32lo, o32hi, OTb);

  // Y[b] = Wr @ O_b + br           (256x1024, K=512), BM=64 -> 256 blocks
  gemm_nt<64, true><<<dim3(8, 4, 8), 256, 0, stream>>>(Wrb, OTb, out, br,
      256, 1024, 512, 512, 512, 1024,
      0L, 0L, 524288L, 0L, 262144L, 0L, 1);
}